// Round 6
// baseline (1109.185 us; speedup 1.0000x reference)
//
#include <hip/hip_runtime.h>
#include <math.h>

#define VOCAB 50000
#define EMB 300
#define NB 128
#define TQ 32
#define TD 4096
#define TOPK 20
#define NCHUNK 8             // blocks per batch along doc axis
#define TOKS_PER_BLOCK 512   // TD / NCHUNK; two tokens per thread
#define NHC 75               // EMB / 4

// ---------------- Kernel 1: per-row inverse norms of emb_table ----------------
__global__ __launch_bounds__(256) void rownorm_kernel(const float* __restrict__ emb,
                                                      float* __restrict__ invn) {
  int row = blockIdx.x * 4 + (threadIdx.x >> 6);
  if (row >= VOCAB) return;
  int lane = threadIdx.x & 63;
  float s = 0.f;
  for (int h = lane; h < EMB; h += 64) {
    float v = emb[row * EMB + h];
    s += v * v;
  }
#pragma unroll
  for (int off = 32; off; off >>= 1) s += __shfl_xor(s, off, 64);
  if (lane == 0) invn[row] = 1.0f / fmaxf(sqrtf(s), 1e-8f);
}

// ---------------- Kernel 1b: normalized query embeddings, transposed ----------------
// qn_t layout: [b][hc][q][4]  (hc = h/4) -> one contiguous 38.4KB slab per b
__global__ __launch_bounds__(256) void qprep_kernel(const int* __restrict__ query,
                                                    const float* __restrict__ emb,
                                                    const float* __restrict__ invn,
                                                    float* __restrict__ qn_t) {
  const int b = blockIdx.x;
  for (int i = (int)threadIdx.x; i < NHC * TQ; i += 256) {
    int hc = i >> 5, q = i & 31;
    int tok = query[b * TQ + q];
    float inv = invn[tok];
    float4 v = *(const float4*)(emb + (size_t)tok * EMB + hc * 4);
    float4 o;
    o.x = v.x * inv; o.y = v.y * inv; o.z = v.z * inv; o.w = v.w * inv;
    *(float4*)(qn_t + (((size_t)b * NHC + hc) * TQ + q) * 4) = o;
  }
}

// ---------------- Kernel 2: cosine + per-block top-k ----------------
// grid = (NCHUNK, NB), block = 256 (4 waves); each lane owns TWO doc tokens.
// Per hc-step: 32 uniform ds_read_b128 (broadcast) feed 256 FMAs (1:8) --
// this halves the per-CU LDS-pipe demand per FLOP vs R5 (which was LDS-bound
// at VALUBusy 45%). 64 fp32 acc + depth-3 ring x2 streams ~ 130 VGPR, well
// under the 168 cap at (256,3): no fission pressure (fission shows as
// VGPR~70 + FETCH ~750MB; success shows VGPR>=120 + FETCH ~380MB).
__global__ __launch_bounds__(256, 3) void cos_topk_kernel(
    const int* __restrict__ doc, const float* __restrict__ emb,
    const float* __restrict__ invn, const float* __restrict__ qn_t,
    float* __restrict__ partial /* [NB][NCHUNK][TQ][TOPK] */) {
  __shared__ __align__(16) float smem[9600];  // qsh, later reused as costmp
  __shared__ float topv[4][TQ][21];           // per-wave sorted-desc top-20

  float* qsh = smem;
  float (*costmp)[33] = (float (*)[33])smem;  // [wave*64 + tok][q], pad 33

  const int b = blockIdx.y;
  const int chunk = blockIdx.x;
  const int tid = (int)threadIdx.x;
  const int wave = tid >> 6;
  const int lane = tid & 63;

  // stage this batch's normalized query slab into LDS (linear copy, float4)
  {
    const float4* src = (const float4*)(qn_t + (size_t)b * (NHC * TQ * 4));
    float4* dst = (float4*)qsh;
    for (int i = tid; i < NHC * TQ; i += 256) dst[i] = src[i];
  }
  if (lane < TQ) {
#pragma unroll
    for (int k = 0; k < TOPK; ++k) topv[wave][lane][k] = -2.0f;
  }
  __syncthreads();  // qsh ready

  const int t0 = chunk * TOKS_PER_BLOCK;
  const int tokA = doc[b * TD + t0 + tid];
  const int tokB = doc[b * TD + t0 + 256 + tid];
  const float invdA = invn[tokA];
  const float invdB = invn[tokB];
  const float* __restrict__ drowA = emb + (size_t)tokA * EMB;
  const float* __restrict__ drowB = emb + (size_t)tokB * EMB;

  float acc0[TQ], acc1[TQ];
#pragma unroll
  for (int qi = 0; qi < TQ; ++qi) { acc0[qi] = 0.f; acc1[qi] = 0.f; }

  // depth-3 prefetch ring per stream, all slot names static; 75 = 3*25 rounds
  float4 a0 = *(const float4*)(drowA + 0);
  float4 a1 = *(const float4*)(drowA + 4);
  float4 a2 = *(const float4*)(drowA + 8);
  float4 b0 = *(const float4*)(drowB + 0);
  float4 b1 = *(const float4*)(drowB + 4);
  float4 b2 = *(const float4*)(drowB + 8);

#define STEP(S, PA, PB)                                                        \
  {                                                                            \
    const float4 da = PA;                                                      \
    const float4 db = PB;                                                      \
    PA = *(const float4*)(drowA + 4 * (hcb + S + 3));                          \
    PB = *(const float4*)(drowB + 4 * (hcb + S + 3));                          \
    const float* __restrict__ qc = qsh + (hcb + S) * (TQ * 4);                 \
    _Pragma("unroll") for (int qi = 0; qi < TQ; ++qi) {                        \
      float4 qf = *(const float4*)(qc + qi * 4); /* uniform -> broadcast */    \
      acc0[qi] =                                                               \
          fmaf(qf.x, da.x, fmaf(qf.y, da.y, fmaf(qf.z, da.z, fmaf(qf.w, da.w, acc0[qi])))); \
      acc1[qi] =                                                               \
          fmaf(qf.x, db.x, fmaf(qf.y, db.y, fmaf(qf.z, db.z, fmaf(qf.w, db.w, acc1[qi])))); \
    }                                                                          \
  }
#define STEP_LAST(S, PA, PB)                                                   \
  {                                                                            \
    const float4 da = PA;                                                      \
    const float4 db = PB;                                                      \
    const float* __restrict__ qc = qsh + (hcb + S) * (TQ * 4);                 \
    _Pragma("unroll") for (int qi = 0; qi < TQ; ++qi) {                        \
      float4 qf = *(const float4*)(qc + qi * 4);                               \
      acc0[qi] =                                                               \
          fmaf(qf.x, da.x, fmaf(qf.y, da.y, fmaf(qf.z, da.z, fmaf(qf.w, da.w, acc0[qi])))); \
      acc1[qi] =                                                               \
          fmaf(qf.x, db.x, fmaf(qf.y, db.y, fmaf(qf.z, db.z, fmaf(qf.w, db.w, acc1[qi])))); \
    }                                                                          \
  }

#pragma unroll 1
  for (int r = 0; r < 24; ++r) {
    const int hcb = r * 3;
    STEP(0, a0, b0)
    STEP(1, a1, b1)
    STEP(2, a2, b2)
  }
  {
    const int hcb = 72;  // final round, no reload (avoids OOB past row end)
    STEP_LAST(0, a0, b0)
    STEP_LAST(1, a1, b1)
    STEP_LAST(2, a2, b2)
  }
#undef STEP
#undef STEP_LAST

  // 2 macro-unrolled top-k passes; __syncthreads orders LDS reuse between
  // passes (and fences the compiler). All acc indexing static.
#define TOPK_PASS(ACC, INVD)                                        \
  __syncthreads();                                                  \
  {                                                                 \
    _Pragma("unroll") for (int qi = 0; qi < TQ; ++qi)               \
        costmp[wave * 64 + lane][qi] = ACC[qi] * INVD;              \
    if (lane < TQ) {                                                \
      const int q = lane;                                           \
      float* tv = &topv[wave][q][0];                                \
      float mn = tv[TOPK - 1];                                      \
      for (int tt = 0; tt < 64; ++tt) {                             \
        float v = costmp[wave * 64 + tt][q];                        \
        if (v > mn) {                                               \
          int p = TOPK - 1;                                         \
          while (p > 0 && tv[p - 1] < v) {                          \
            tv[p] = tv[p - 1];                                      \
            --p;                                                    \
          }                                                         \
          tv[p] = v;                                                \
          mn = tv[TOPK - 1];                                        \
        }                                                           \
      }                                                             \
    }                                                               \
  }

  TOPK_PASS(acc0, invdA)
  TOPK_PASS(acc1, invdB)
#undef TOPK_PASS
  __syncthreads();

  // combine 4 wave lists into topv[0]
  if (tid < TQ) {
    const int q = tid;
    float* dst = &topv[0][q][0];
#pragma unroll
    for (int w = 1; w < 4; ++w) {
      for (int k = 0; k < TOPK; ++k) {
        float v = topv[w][q][k];
        if (v <= dst[TOPK - 1]) break;
        int p = TOPK - 1;
        while (p > 0 && dst[p - 1] < v) {
          dst[p] = dst[p - 1];
          --p;
        }
        dst[p] = v;
      }
    }
  }
  __syncthreads();

  for (int i = tid; i < TQ * TOPK; i += 256)
    partial[((size_t)(b * NCHUNK + chunk)) * (TQ * TOPK) + i] =
        topv[0][i / TOPK][i % TOPK];
}

// ---------------- Kernel 3: merge partials, FFW+tanh, gated softmax ----------------
__global__ __launch_bounds__(64) void finalize_kernel(
    const float* __restrict__ partial, const int* __restrict__ query,
    const float* __restrict__ qidf, const float* __restrict__ ffw_W,
    const float* __restrict__ ffw_b, const float* __restrict__ gates_W,
    const float* __restrict__ out_W, const float* __restrict__ out_b,
    float* __restrict__ out) {
  const int b = blockIdx.x;
  const int lane = (int)threadIdx.x;  // 0..63
  float ffw = 0.f;
  float logit = -3e38f;
  if (lane < TQ) {
    const int q = lane;
    int pos[NCHUNK];
#pragma unroll
    for (int c = 0; c < NCHUNK; ++c) pos[c] = 0;
    float s = 0.f;
    for (int k = 0; k < TOPK; ++k) {
      float best = -4.f;
      int bi = 0;
#pragma unroll
      for (int c = 0; c < NCHUNK; ++c) {
        float v = (pos[c] < TOPK)
                      ? partial[((size_t)(b * NCHUNK + c) * TQ + q) * TOPK + pos[c]]
                      : -4.f;
        if (v > best) {
          best = v;
          bi = c;
        }
      }
#pragma unroll
      for (int c = 0; c < NCHUNK; ++c)
        if (c == bi) pos[c]++;
      s += best * ffw_W[k];
    }
    ffw = tanhf(s + ffw_b[0]);
    int tok = query[b * TQ + q];
    logit = qidf[b * TQ + q] * gates_W[0] + (tok == 0 ? -1e7f : 0.f);
  }
  float m = logit;
#pragma unroll
  for (int off = 32; off; off >>= 1) m = fmaxf(m, __shfl_xor(m, off, 64));
  float e = expf(logit - m);
  float num = e * ffw;
  float den = e;
#pragma unroll
  for (int off = 32; off; off >>= 1) {
    num += __shfl_xor(num, off, 64);
    den += __shfl_xor(den, off, 64);
  }
  if (lane == 0) out[b] = (num / den) * out_W[0] + out_b[0];
}

extern "C" void kernel_launch(void* const* d_in, const int* in_sizes, int n_in,
                              void* d_out, int out_size, void* d_ws, size_t ws_size,
                              hipStream_t stream) {
  const int* doc = (const int*)d_in[0];
  const int* query = (const int*)d_in[1];
  const float* qidf = (const float*)d_in[2];
  const float* emb = (const float*)d_in[3];
  const float* ffw_W = (const float*)d_in[4];
  const float* ffw_b = (const float*)d_in[5];
  const float* gates_W = (const float*)d_in[6];
  const float* out_W = (const float*)d_in[7];
  const float* out_b = (const float*)d_in[8];
  float* out = (float*)d_out;

  float* invn = (float*)d_ws;                         // 50048 floats
  float* qn_t = invn + 50048;                         // 128*75*32*4 = 1228800
  float* partial = qn_t + (size_t)NB * NHC * TQ * 4;  // 128*8*32*20 = 655360

  rownorm_kernel<<<(VOCAB + 3) / 4, 256, 0, stream>>>(emb, invn);
  qprep_kernel<<<NB, 256, 0, stream>>>(query, emb, invn, qn_t);
  dim3 grid(NCHUNK, NB);
  cos_topk_kernel<<<grid, 256, 0, stream>>>(doc, emb, invn, qn_t, partial);
  finalize_kernel<<<NB, 64, 0, stream>>>(partial, query, qidf, ffw_W, ffw_b,
                                         gates_W, out_W, out_b, out);
}

// Round 7
// 388.044 us; speedup vs baseline: 2.8584x; 2.8584x over previous
//
#include <hip/hip_runtime.h>
#include <math.h>

#define VOCAB 50000
#define EMB 300
#define NB 128
#define TQ 32
#define TD 4096
#define TOPK 20
#define KP 320               // padded K (10 x 32)
#define NCHUNK 16            // doc chunks (both paths)
#define NHC 75               // EMB/4 (fallback path)

typedef short short8 __attribute__((ext_vector_type(8)));
typedef float f32x4 __attribute__((ext_vector_type(4)));

// ---- RTNE float -> bf16 split helpers (device) ----
__device__ inline ushort bf16_rtne(float x) {
  unsigned u = __float_as_uint(x);
  unsigned r = u + 0x7fffu + ((u >> 16) & 1u);
  return (ushort)(r >> 16);
}

// ---------------- Kernel 1: per-row inverse norms ----------------
__global__ __launch_bounds__(256) void rownorm_kernel(const float* __restrict__ emb,
                                                      float* __restrict__ invn) {
  int row = blockIdx.x * 4 + (threadIdx.x >> 6);
  if (row >= VOCAB) return;
  int lane = threadIdx.x & 63;
  float s = 0.f;
  for (int h = lane; h < EMB; h += 64) {
    float v = emb[row * EMB + h];
    s += v * v;
  }
#pragma unroll
  for (int off = 32; off; off >>= 1) s += __shfl_xor(s, off, 64);
  if (lane == 0) invn[row] = 1.0f / fmaxf(sqrtf(s), 1e-8f);
}

// ---------------- MFMA path prep: normalized, split, padded tables ----------------
__global__ __launch_bounds__(256) void dprep_kernel(const float* __restrict__ emb,
                                                    const float* __restrict__ invn,
                                                    ushort* __restrict__ dhi,
                                                    ushort* __restrict__ dlo) {
  int row = blockIdx.x * 4 + (threadIdx.x >> 6);
  if (row >= VOCAB) return;
  int lane = threadIdx.x & 63;
  float inv = invn[row];
#pragma unroll
  for (int j = 0; j < 5; ++j) {
    int k = j * 64 + lane;
    float x = (k < EMB) ? emb[(size_t)row * EMB + k] * inv : 0.f;
    ushort h = bf16_rtne(x);
    float hf = __uint_as_float((unsigned)h << 16);
    ushort l = bf16_rtne(x - hf);
    dhi[(size_t)row * KP + k] = h;
    dlo[(size_t)row * KP + k] = l;
  }
}

__global__ __launch_bounds__(256) void qprep2_kernel(const int* __restrict__ query,
                                                     const float* __restrict__ emb,
                                                     const float* __restrict__ invn,
                                                     ushort* __restrict__ qhi,
                                                     ushort* __restrict__ qlo) {
  const int b = blockIdx.x;
  for (int i = (int)threadIdx.x; i < TQ * KP; i += 256) {
    int q = i / KP, k = i - q * KP;
    int tok = query[b * TQ + q];
    float x = (k < EMB) ? emb[(size_t)tok * EMB + k] * invn[tok] : 0.f;
    ushort h = bf16_rtne(x);
    float hf = __uint_as_float((unsigned)h << 16);
    ushort l = bf16_rtne(x - hf);
    qhi[(size_t)(b * TQ + q) * KP + k] = h;
    qlo[(size_t)(b * TQ + q) * KP + k] = l;
  }
}

// ---------------- MFMA main: S = Qn.Dn^T (split bf16), per-chunk top-k ----------------
// grid (16, NB), block 256 (4 waves). Wave: 32q x 64 tokens, 8 named f32x4 acc.
// Frags load straight from bf16 tables: lane c=lane&15 (A row / B col),
// kg=lane>>4 -> 16 contiguous bytes at k-offset ks*32+kg*8 (m97-verified layout).
__global__ __launch_bounds__(256, 3) void mfma_topk_kernel(
    const int* __restrict__ doc, const ushort* __restrict__ qhi,
    const ushort* __restrict__ qlo, const ushort* __restrict__ dhi,
    const ushort* __restrict__ dlo, float* __restrict__ partial) {
  __shared__ float costmp[4][64][33];  // [wave][token][q], pad 33
  __shared__ float topv[4][TQ][21];

  const int b = blockIdx.y;
  const int chunk = blockIdx.x;
  const int tid = (int)threadIdx.x;
  const int wave = tid >> 6;
  const int lane = tid & 63;
  const int c = lane & 15;
  const int kg = lane >> 4;

  const int tbase = b * TD + chunk * 256 + wave * 64;
  const int doff0 = doc[tbase + 0 * 16 + c] * KP;
  const int doff1 = doc[tbase + 1 * 16 + c] * KP;
  const int doff2 = doc[tbase + 2 * 16 + c] * KP;
  const int doff3 = doc[tbase + 3 * 16 + c] * KP;
  const int qoff0 = (b * TQ + 0 * 16 + c) * KP;
  const int qoff1 = (b * TQ + 16 + c) * KP;

  f32x4 a00 = {0.f, 0.f, 0.f, 0.f}, a01 = a00, a02 = a00, a03 = a00;
  f32x4 a10 = a00, a11 = a00, a12 = a00, a13 = a00;

#define MM3(ACC, AH, AL, BH, BL)                                          \
  ACC = __builtin_amdgcn_mfma_f32_16x16x32_bf16(AH, BH, ACC, 0, 0, 0);    \
  ACC = __builtin_amdgcn_mfma_f32_16x16x32_bf16(AH, BL, ACC, 0, 0, 0);    \
  ACC = __builtin_amdgcn_mfma_f32_16x16x32_bf16(AL, BH, ACC, 0, 0, 0);

#pragma unroll 2
  for (int ks = 0; ks < KP / 32; ++ks) {
    const int ko = ks * 32 + kg * 8;
    short8 ah0 = *(const short8*)(qhi + qoff0 + ko);
    short8 ah1 = *(const short8*)(qhi + qoff1 + ko);
    short8 al0 = *(const short8*)(qlo + qoff0 + ko);
    short8 al1 = *(const short8*)(qlo + qoff1 + ko);
    short8 bh0 = *(const short8*)(dhi + doff0 + ko);
    short8 bh1 = *(const short8*)(dhi + doff1 + ko);
    short8 bh2 = *(const short8*)(dhi + doff2 + ko);
    short8 bh3 = *(const short8*)(dhi + doff3 + ko);
    short8 bl0 = *(const short8*)(dlo + doff0 + ko);
    short8 bl1 = *(const short8*)(dlo + doff1 + ko);
    short8 bl2 = *(const short8*)(dlo + doff2 + ko);
    short8 bl3 = *(const short8*)(dlo + doff3 + ko);
    MM3(a00, ah0, al0, bh0, bl0)
    MM3(a01, ah0, al0, bh1, bl1)
    MM3(a02, ah0, al0, bh2, bl2)
    MM3(a03, ah0, al0, bh3, bl3)
    MM3(a10, ah1, al1, bh0, bl0)
    MM3(a11, ah1, al1, bh1, bl1)
    MM3(a12, ah1, al1, bh2, bl2)
    MM3(a13, ah1, al1, bh3, bl3)
  }
#undef MM3

  // scatter C tiles to costmp: C col=lane&15 (token), row=kg*4+reg (q in tile)
#define WT(ACC, M, NT)                                      \
  {                                                         \
    float* dst = &costmp[wave][NT * 16 + c][M * 16 + kg * 4]; \
    dst[0] = ACC[0]; dst[1] = ACC[1];                       \
    dst[2] = ACC[2]; dst[3] = ACC[3];                       \
  }
  WT(a00, 0, 0) WT(a01, 0, 1) WT(a02, 0, 2) WT(a03, 0, 3)
  WT(a10, 1, 0) WT(a11, 1, 1) WT(a12, 1, 2) WT(a13, 1, 3)
#undef WT

  // init + per-wave top-20 scan over this wave's 64 tokens (R5-proven)
  if (lane < TQ) {
    const int q = lane;
    float tvreg[TOPK];
#pragma unroll
    for (int k = 0; k < TOPK; ++k) tvreg[k] = -2.0f;
    float* tv = &topv[wave][q][0];
#pragma unroll
    for (int k = 0; k < TOPK; ++k) tv[k] = tvreg[k];
    float mn = -2.0f;
    for (int tt = 0; tt < 64; ++tt) {
      float v = costmp[wave][tt][q];
      if (v > mn) {
        int p = TOPK - 1;
        while (p > 0 && tv[p - 1] < v) {
          tv[p] = tv[p - 1];
          --p;
        }
        tv[p] = v;
        mn = tv[TOPK - 1];
      }
    }
  }
  __syncthreads();

  // combine 4 wave lists into topv[0]
  if (tid < TQ) {
    const int q = tid;
    float* dst = &topv[0][q][0];
#pragma unroll
    for (int w = 1; w < 4; ++w) {
      for (int k = 0; k < TOPK; ++k) {
        float v = topv[w][q][k];
        if (v <= dst[TOPK - 1]) break;
        int p = TOPK - 1;
        while (p > 0 && dst[p - 1] < v) {
          dst[p] = dst[p - 1];
          --p;
        }
        dst[p] = v;
      }
    }
  }
  __syncthreads();

  for (int i = tid; i < TQ * TOPK; i += 256)
    partial[((size_t)(b * NCHUNK + chunk)) * (TQ * TOPK) + i] =
        topv[0][i / TOPK][i % TOPK];
}

// ---------------- Fallback path (R5, proven 476us): fp32 VALU ----------------
__global__ __launch_bounds__(256) void qprep_kernel(const int* __restrict__ query,
                                                    const float* __restrict__ emb,
                                                    const float* __restrict__ invn,
                                                    float* __restrict__ qn_t) {
  const int b = blockIdx.x;
  for (int i = (int)threadIdx.x; i < NHC * TQ; i += 256) {
    int hc = i >> 5, q = i & 31;
    int tok = query[b * TQ + q];
    float inv = invn[tok];
    float4 v = *(const float4*)(emb + (size_t)tok * EMB + hc * 4);
    float4 o;
    o.x = v.x * inv; o.y = v.y * inv; o.z = v.z * inv; o.w = v.w * inv;
    *(float4*)(qn_t + (((size_t)b * NHC + hc) * TQ + q) * 4) = o;
  }
}

__global__ __launch_bounds__(256, 3) void cos_topk_kernel(
    const int* __restrict__ doc, const float* __restrict__ emb,
    const float* __restrict__ invn, const float* __restrict__ qn_t,
    float* __restrict__ partial) {
  __shared__ __align__(16) float smem[9600];
  __shared__ float topv[4][TQ][21];
  float* qsh = smem;
  float (*costmp)[33] = (float (*)[33])smem;

  const int b = blockIdx.y;
  const int chunk = blockIdx.x;
  const int tid = (int)threadIdx.x;
  const int wave = tid >> 6;
  const int lane = tid & 63;

  {
    const float4* src = (const float4*)(qn_t + (size_t)b * (NHC * TQ * 4));
    float4* dst = (float4*)qsh;
    for (int i = tid; i < NHC * TQ; i += 256) dst[i] = src[i];
  }
  if (lane < TQ) {
#pragma unroll
    for (int k = 0; k < TOPK; ++k) topv[wave][lane][k] = -2.0f;
  }
  __syncthreads();

  const int tok = doc[b * TD + chunk * 256 + tid];
  const float invd = invn[tok];
  const float* __restrict__ drow = emb + (size_t)tok * EMB;

  float acc[TQ];
#pragma unroll
  for (int qi = 0; qi < TQ; ++qi) acc[qi] = 0.f;

  float4 p0 = *(const float4*)(drow + 0);
  float4 p1 = *(const float4*)(drow + 4);
  float4 p2 = *(const float4*)(drow + 8);
  float4 p3 = *(const float4*)(drow + 12);
  float4 p4 = *(const float4*)(drow + 16);

#define STEP(S, PS)                                                           \
  {                                                                           \
    const float4 d = PS;                                                      \
    PS = *(const float4*)(drow + 4 * (hcb + S + 5));                          \
    const float* __restrict__ qc = qsh + (hcb + S) * (TQ * 4);                \
    _Pragma("unroll") for (int qi = 0; qi < TQ; ++qi) {                       \
      float4 qf = *(const float4*)(qc + qi * 4);                              \
      acc[qi] =                                                               \
          fmaf(qf.x, d.x, fmaf(qf.y, d.y, fmaf(qf.z, d.z, fmaf(qf.w, d.w, acc[qi])))); \
    }                                                                         \
  }
#define STEP_LAST(S, PS)                                                      \
  {                                                                           \
    const float4 d = PS;                                                      \
    const float* __restrict__ qc = qsh + (hcb + S) * (TQ * 4);                \
    _Pragma("unroll") for (int qi = 0; qi < TQ; ++qi) {                       \
      float4 qf = *(const float4*)(qc + qi * 4);                              \
      acc[qi] =                                                               \
          fmaf(qf.x, d.x, fmaf(qf.y, d.y, fmaf(qf.z, d.z, fmaf(qf.w, d.w, acc[qi])))); \
    }                                                                         \
  }
#pragma unroll 1
  for (int r = 0; r < 14; ++r) {
    const int hcb = r * 5;
    STEP(0, p0) STEP(1, p1) STEP(2, p2) STEP(3, p3) STEP(4, p4)
  }
  {
    const int hcb = 70;
    STEP_LAST(0, p0) STEP_LAST(1, p1) STEP_LAST(2, p2) STEP_LAST(3, p3) STEP_LAST(4, p4)
  }
#undef STEP
#undef STEP_LAST

  __syncthreads();
#pragma unroll
  for (int qi = 0; qi < TQ; ++qi) costmp[wave * 64 + lane][qi] = acc[qi] * invd;

  if (lane < TQ) {
    const int q = lane;
    float* tv = &topv[wave][q][0];
    float mn = tv[TOPK - 1];
    for (int tt = 0; tt < 64; ++tt) {
      float v = costmp[wave * 64 + tt][q];
      if (v > mn) {
        int p = TOPK - 1;
        while (p > 0 && tv[p - 1] < v) {
          tv[p] = tv[p - 1];
          --p;
        }
        tv[p] = v;
        mn = tv[TOPK - 1];
      }
    }
  }
  __syncthreads();

  if (tid < TQ) {
    const int q = tid;
    float* dst = &topv[0][q][0];
#pragma unroll
    for (int w = 1; w < 4; ++w) {
      for (int k = 0; k < TOPK; ++k) {
        float v = topv[w][q][k];
        if (v <= dst[TOPK - 1]) break;
        int p = TOPK - 1;
        while (p > 0 && dst[p - 1] < v) {
          dst[p] = dst[p - 1];
          --p;
        }
        dst[p] = v;
      }
    }
  }
  __syncthreads();

  for (int i = tid; i < TQ * TOPK; i += 256)
    partial[((size_t)(b * NCHUNK + chunk)) * (TQ * TOPK) + i] =
        topv[0][i / TOPK][i % TOPK];
}

// ---------------- Kernel 3: merge partials, FFW+tanh, gated softmax ----------------
__global__ __launch_bounds__(64) void finalize_kernel(
    const float* __restrict__ partial, const int* __restrict__ query,
    const float* __restrict__ qidf, const float* __restrict__ ffw_W,
    const float* __restrict__ ffw_b, const float* __restrict__ gates_W,
    const float* __restrict__ out_W, const float* __restrict__ out_b,
    float* __restrict__ out) {
  const int b = blockIdx.x;
  const int lane = (int)threadIdx.x;
  float ffw = 0.f;
  float logit = -3e38f;
  if (lane < TQ) {
    const int q = lane;
    int pos[NCHUNK];
#pragma unroll
    for (int c = 0; c < NCHUNK; ++c) pos[c] = 0;
    float s = 0.f;
    for (int k = 0; k < TOPK; ++k) {
      float best = -4.f;
      int bi = 0;
#pragma unroll
      for (int c = 0; c < NCHUNK; ++c) {
        float v = (pos[c] < TOPK)
                      ? partial[((size_t)(b * NCHUNK + c) * TQ + q) * TOPK + pos[c]]
                      : -4.f;
        if (v > best) {
          best = v;
          bi = c;
        }
      }
#pragma unroll
      for (int c = 0; c < NCHUNK; ++c)
        if (c == bi) pos[c]++;
      s += best * ffw_W[k];
    }
    ffw = tanhf(s + ffw_b[0]);
    int tok = query[b * TQ + q];
    logit = qidf[b * TQ + q] * gates_W[0] + (tok == 0 ? -1e7f : 0.f);
  }
  float m = logit;
#pragma unroll
  for (int off = 32; off; off >>= 1) m = fmaxf(m, __shfl_xor(m, off, 64));
  float e = expf(logit - m);
  float num = e * ffw;
  float den = e;
#pragma unroll
  for (int off = 32; off; off >>= 1) {
    num += __shfl_xor(num, off, 64);
    den += __shfl_xor(den, off, 64);
  }
  if (lane == 0) out[b] = (num / den) * out_W[0] + out_b[0];
}

extern "C" void kernel_launch(void* const* d_in, const int* in_sizes, int n_in,
                              void* d_out, int out_size, void* d_ws, size_t ws_size,
                              hipStream_t stream) {
  const int* doc = (const int*)d_in[0];
  const int* query = (const int*)d_in[1];
  const float* qidf = (const float*)d_in[2];
  const float* emb = (const float*)d_in[3];
  const float* ffw_W = (const float*)d_in[4];
  const float* ffw_b = (const float*)d_in[5];
  const float* gates_W = (const float*)d_in[6];
  const float* out_W = (const float*)d_in[7];
  const float* out_b = (const float*)d_in[8];
  float* out = (float*)d_out;

  char* ws = (char*)d_ws;
  float* invn = (float*)ws;  // 50048 floats = 200192 B

  // MFMA-path layout (bytes): invn 200192 | qhi 2621440 | qlo 2621440 |
  // dhi 32000000 | dlo 32000000 | partial 5242880  => 74685952 total
  const size_t OFF_QHI = 200192;
  const size_t OFF_QLO = OFF_QHI + (size_t)NB * TQ * KP * 2;
  const size_t OFF_DHI = OFF_QLO + (size_t)NB * TQ * KP * 2;
  const size_t OFF_DLO = OFF_DHI + (size_t)VOCAB * KP * 2;
  const size_t OFF_PAR = OFF_DLO + (size_t)VOCAB * KP * 2;
  const size_t NEED = OFF_PAR + (size_t)NB * NCHUNK * TQ * TOPK * 4;

  rownorm_kernel<<<(VOCAB + 3) / 4, 256, 0, stream>>>(emb, invn);

  if (ws_size >= NEED) {
    ushort* qhi = (ushort*)(ws + OFF_QHI);
    ushort* qlo = (ushort*)(ws + OFF_QLO);
    ushort* dhi = (ushort*)(ws + OFF_DHI);
    ushort* dlo = (ushort*)(ws + OFF_DLO);
    float* partial = (float*)(ws + OFF_PAR);
    dprep_kernel<<<(VOCAB + 3) / 4, 256, 0, stream>>>(emb, invn, dhi, dlo);
    qprep2_kernel<<<NB, 256, 0, stream>>>(query, emb, invn, qhi, qlo);
    dim3 grid(NCHUNK, NB);
    mfma_topk_kernel<<<grid, 256, 0, stream>>>(doc, qhi, qlo, dhi, dlo, partial);
    finalize_kernel<<<NB, 64, 0, stream>>>(partial, query, qidf, ffw_W, ffw_b,
                                           gates_W, out_W, out_b, out);
  } else {
    // R5 fallback: invn | qn_t (1228800 f) | partial (1310720 f) ~ 10.4 MB
    float* qn_t = invn + 50048;
    float* partial = qn_t + (size_t)NB * NHC * TQ * 4;
    qprep_kernel<<<NB, 256, 0, stream>>>(query, emb, invn, qn_t);
    dim3 grid(NCHUNK, NB);
    cos_topk_kernel<<<grid, 256, 0, stream>>>(doc, emb, invn, qn_t, partial);
    finalize_kernel<<<NB, 64, 0, stream>>>(partial, query, qidf, ffw_W, ffw_b,
                                           gates_W, out_W, out_b, out);
  }
}

// Round 8
// 355.327 us; speedup vs baseline: 3.1216x; 1.0921x over previous
//
#include <hip/hip_runtime.h>
#include <math.h>

#define VOCAB 50000
#define EMB 300
#define NB 128
#define TQ 32
#define TD 4096
#define TOPK 20
#define KP 320               // padded K (10 x 32)
#define NCHUNK 16            // doc chunks (both paths)
#define NHC 75               // EMB/4 (fallback path)

typedef short short8 __attribute__((ext_vector_type(8)));
typedef float f32x4 __attribute__((ext_vector_type(4)));

// ---- RTNE float -> bf16 split helpers (device) ----
__device__ inline ushort bf16_rtne(float x) {
  unsigned u = __float_as_uint(x);
  unsigned r = u + 0x7fffu + ((u >> 16) & 1u);
  return (ushort)(r >> 16);
}

// ---------------- Kernel 1 (fallback only): per-row inverse norms ----------------
__global__ __launch_bounds__(256) void rownorm_kernel(const float* __restrict__ emb,
                                                      float* __restrict__ invn) {
  int row = blockIdx.x * 4 + (threadIdx.x >> 6);
  if (row >= VOCAB) return;
  int lane = threadIdx.x & 63;
  float s = 0.f;
  for (int h = lane; h < EMB; h += 64) {
    float v = emb[row * EMB + h];
    s += v * v;
  }
#pragma unroll
  for (int off = 32; off; off >>= 1) s += __shfl_xor(s, off, 64);
  if (lane == 0) invn[row] = 1.0f / fmaxf(sqrtf(s), 1e-8f);
}

// ---------------- MFMA prep: fused norm + split + pad (doc table) ----------------
__global__ __launch_bounds__(256) void dprep_kernel(const float* __restrict__ emb,
                                                    ushort* __restrict__ dhi,
                                                    ushort* __restrict__ dlo) {
  int row = blockIdx.x * 4 + (threadIdx.x >> 6);
  if (row >= VOCAB) return;
  int lane = threadIdx.x & 63;
  float v[5];
  float s = 0.f;
#pragma unroll
  for (int j = 0; j < 5; ++j) {
    int k = j * 64 + lane;
    float x = (k < EMB) ? emb[(size_t)row * EMB + k] : 0.f;
    v[j] = x;
    s += x * x;
  }
#pragma unroll
  for (int off = 32; off; off >>= 1) s += __shfl_xor(s, off, 64);
  float inv = 1.0f / fmaxf(sqrtf(s), 1e-8f);
#pragma unroll
  for (int j = 0; j < 5; ++j) {
    int k = j * 64 + lane;
    float x = v[j] * inv;
    ushort h = bf16_rtne(x);
    float hf = __uint_as_float((unsigned)h << 16);
    ushort l = bf16_rtne(x - hf);
    dhi[(size_t)row * KP + k] = h;
    dlo[(size_t)row * KP + k] = l;
  }
}

__global__ __launch_bounds__(256) void qprep2_kernel(const int* __restrict__ query,
                                                     const float* __restrict__ emb,
                                                     ushort* __restrict__ qhi,
                                                     ushort* __restrict__ qlo) {
  const int b = blockIdx.x;
  const int wave = (int)threadIdx.x >> 6;
  const int lane = (int)threadIdx.x & 63;
#pragma unroll 1
  for (int q = wave; q < TQ; q += 4) {
    int tok = query[b * TQ + q];
    float v[5];
    float s = 0.f;
#pragma unroll
    for (int j = 0; j < 5; ++j) {
      int k = j * 64 + lane;
      float x = (k < EMB) ? emb[(size_t)tok * EMB + k] : 0.f;
      v[j] = x;
      s += x * x;
    }
#pragma unroll
    for (int off = 32; off; off >>= 1) s += __shfl_xor(s, off, 64);
    float inv = 1.0f / fmaxf(sqrtf(s), 1e-8f);
#pragma unroll
    for (int j = 0; j < 5; ++j) {
      int k = j * 64 + lane;
      float x = v[j] * inv;
      ushort h = bf16_rtne(x);
      float hf = __uint_as_float((unsigned)h << 16);
      ushort l = bf16_rtne(x - hf);
      qhi[(size_t)(b * TQ + q) * KP + k] = h;
      qlo[(size_t)(b * TQ + q) * KP + k] = l;
    }
  }
}

// ---------------- MFMA main: software-pipelined fragment gathers ----------------
// grid (16, NB), block 256 (4 waves). Wave: 32q x 64 tokens, 8 named f32x4 acc.
// Two named prefetch sets (P/Q): loads for K-step ks+1 issue BEFORE the MFMAs
// of step ks, so each 3-MFMA cluster runs over gathers issued ~1 iter earlier.
// Expected VGPR ~150 (R7's serialized version showed 72 = compiler reuse).
__global__ __launch_bounds__(256, 3) void mfma_topk_kernel(
    const int* __restrict__ doc, const ushort* __restrict__ qhi,
    const ushort* __restrict__ qlo, const ushort* __restrict__ dhi,
    const ushort* __restrict__ dlo, float* __restrict__ partial) {
  __shared__ float costmp[4][64][33];  // [wave][token][q], pad 33
  __shared__ float topv[4][TQ][21];

  const int b = blockIdx.y;
  const int chunk = blockIdx.x;
  const int tid = (int)threadIdx.x;
  const int wave = tid >> 6;
  const int lane = tid & 63;
  const int c = lane & 15;
  const int kg = lane >> 4;

  const int tbase = b * TD + chunk * 256 + wave * 64;
  const int doff0 = doc[tbase + 0 * 16 + c] * KP;
  const int doff1 = doc[tbase + 1 * 16 + c] * KP;
  const int doff2 = doc[tbase + 2 * 16 + c] * KP;
  const int doff3 = doc[tbase + 3 * 16 + c] * KP;
  const int qoff0 = (b * TQ + 0 * 16 + c) * KP;
  const int qoff1 = (b * TQ + 16 + c) * KP;

  f32x4 a00 = {0.f, 0.f, 0.f, 0.f}, a01 = a00, a02 = a00, a03 = a00;
  f32x4 a10 = a00, a11 = a00, a12 = a00, a13 = a00;

#define DECLSET(S) \
  short8 ah0##S, ah1##S, al0##S, al1##S, bh0##S, bh1##S, bh2##S, bh3##S, \
      bl0##S, bl1##S, bl2##S, bl3##S;
  DECLSET(P)
  DECLSET(Q)
#undef DECLSET

  // NOTE: at KS=10 the addresses run past the row end into the next ws region
  // (allocated: qlo/dhi/dlo/partial follow) -- loaded but never consumed.
#define LOADSET(S, KS)                                     \
  {                                                        \
    const int ko = (KS)*32 + kg * 8;                       \
    ah0##S = *(const short8*)(qhi + qoff0 + ko);           \
    ah1##S = *(const short8*)(qhi + qoff1 + ko);           \
    al0##S = *(const short8*)(qlo + qoff0 + ko);           \
    al1##S = *(const short8*)(qlo + qoff1 + ko);           \
    bh0##S = *(const short8*)(dhi + doff0 + ko);           \
    bh1##S = *(const short8*)(dhi + doff1 + ko);           \
    bh2##S = *(const short8*)(dhi + doff2 + ko);           \
    bh3##S = *(const short8*)(dhi + doff3 + ko);           \
    bl0##S = *(const short8*)(dlo + doff0 + ko);           \
    bl1##S = *(const short8*)(dlo + doff1 + ko);           \
    bl2##S = *(const short8*)(dlo + doff2 + ko);           \
    bl3##S = *(const short8*)(dlo + doff3 + ko);           \
  }

#define MM3(ACC, AH, AL, BH, BL)                                          \
  ACC = __builtin_amdgcn_mfma_f32_16x16x32_bf16(AH, BH, ACC, 0, 0, 0);    \
  ACC = __builtin_amdgcn_mfma_f32_16x16x32_bf16(AH, BL, ACC, 0, 0, 0);    \
  ACC = __builtin_amdgcn_mfma_f32_16x16x32_bf16(AL, BH, ACC, 0, 0, 0);

#define MMALL(S)                           \
  MM3(a00, ah0##S, al0##S, bh0##S, bl0##S) \
  MM3(a01, ah0##S, al0##S, bh1##S, bl1##S) \
  MM3(a02, ah0##S, al0##S, bh2##S, bl2##S) \
  MM3(a03, ah0##S, al0##S, bh3##S, bl3##S) \
  MM3(a10, ah1##S, al1##S, bh0##S, bl0##S) \
  MM3(a11, ah1##S, al1##S, bh1##S, bl1##S) \
  MM3(a12, ah1##S, al1##S, bh2##S, bl2##S) \
  MM3(a13, ah1##S, al1##S, bh3##S, bl3##S)

  LOADSET(P, 0)
#pragma unroll 1
  for (int r = 0; r < 5; ++r) {
    LOADSET(Q, 2 * r + 1)
    MMALL(P)
    LOADSET(P, 2 * r + 2)  // r=4 -> ks=10: prefetch garbage, never consumed
    MMALL(Q)
  }
#undef LOADSET
#undef MM3
#undef MMALL

  // scatter C tiles to costmp: C col=lane&15 (token), row=kg*4+reg (q in tile)
#define WT(ACC, M, NT)                                        \
  {                                                           \
    float* dst = &costmp[wave][NT * 16 + c][M * 16 + kg * 4]; \
    dst[0] = ACC[0]; dst[1] = ACC[1];                         \
    dst[2] = ACC[2]; dst[3] = ACC[3];                         \
  }
  WT(a00, 0, 0) WT(a01, 0, 1) WT(a02, 0, 2) WT(a03, 0, 3)
  WT(a10, 1, 0) WT(a11, 1, 1) WT(a12, 1, 2) WT(a13, 1, 3)
#undef WT

  // per-wave top-20 scan over this wave's 64 tokens (R5-proven)
  if (lane < TQ) {
    const int q = lane;
    float* tv = &topv[wave][q][0];
#pragma unroll
    for (int k = 0; k < TOPK; ++k) tv[k] = -2.0f;
    float mn = -2.0f;
    for (int tt = 0; tt < 64; ++tt) {
      float v = costmp[wave][tt][q];
      if (v > mn) {
        int p = TOPK - 1;
        while (p > 0 && tv[p - 1] < v) {
          tv[p] = tv[p - 1];
          --p;
        }
        tv[p] = v;
        mn = tv[TOPK - 1];
      }
    }
  }
  __syncthreads();

  // combine 4 wave lists into topv[0]
  if (tid < TQ) {
    const int q = tid;
    float* dst = &topv[0][q][0];
#pragma unroll
    for (int w = 1; w < 4; ++w) {
      for (int k = 0; k < TOPK; ++k) {
        float v = topv[w][q][k];
        if (v <= dst[TOPK - 1]) break;
        int p = TOPK - 1;
        while (p > 0 && dst[p - 1] < v) {
          dst[p] = dst[p - 1];
          --p;
        }
        dst[p] = v;
      }
    }
  }
  __syncthreads();

  for (int i = tid; i < TQ * TOPK; i += 256)
    partial[((size_t)(b * NCHUNK + chunk)) * (TQ * TOPK) + i] =
        topv[0][i / TOPK][i % TOPK];
}

// ---------------- Fallback path (R5, proven 476us): fp32 VALU ----------------
__global__ __launch_bounds__(256) void qprep_kernel(const int* __restrict__ query,
                                                    const float* __restrict__ emb,
                                                    const float* __restrict__ invn,
                                                    float* __restrict__ qn_t) {
  const int b = blockIdx.x;
  for (int i = (int)threadIdx.x; i < NHC * TQ; i += 256) {
    int hc = i >> 5, q = i & 31;
    int tok = query[b * TQ + q];
    float inv = invn[tok];
    float4 v = *(const float4*)(emb + (size_t)tok * EMB + hc * 4);
    float4 o;
    o.x = v.x * inv; o.y = v.y * inv; o.z = v.z * inv; o.w = v.w * inv;
    *(float4*)(qn_t + (((size_t)b * NHC + hc) * TQ + q) * 4) = o;
  }
}

__global__ __launch_bounds__(256, 3) void cos_topk_kernel(
    const int* __restrict__ doc, const float* __restrict__ emb,
    const float* __restrict__ invn, const float* __restrict__ qn_t,
    float* __restrict__ partial) {
  __shared__ __align__(16) float smem[9600];
  __shared__ float topv[4][TQ][21];
  float* qsh = smem;
  float (*costmp)[33] = (float (*)[33])smem;

  const int b = blockIdx.y;
  const int chunk = blockIdx.x;
  const int tid = (int)threadIdx.x;
  const int wave = tid >> 6;
  const int lane = tid & 63;

  {
    const float4* src = (const float4*)(qn_t + (size_t)b * (NHC * TQ * 4));
    float4* dst = (float4*)qsh;
    for (int i = tid; i < NHC * TQ; i += 256) dst[i] = src[i];
  }
  if (lane < TQ) {
#pragma unroll
    for (int k = 0; k < TOPK; ++k) topv[wave][lane][k] = -2.0f;
  }
  __syncthreads();

  const int tok = doc[b * TD + chunk * 256 + tid];
  const float invd = invn[tok];
  const float* __restrict__ drow = emb + (size_t)tok * EMB;

  float acc[TQ];
#pragma unroll
  for (int qi = 0; qi < TQ; ++qi) acc[qi] = 0.f;

  float4 p0 = *(const float4*)(drow + 0);
  float4 p1 = *(const float4*)(drow + 4);
  float4 p2 = *(const float4*)(drow + 8);
  float4 p3 = *(const float4*)(drow + 12);
  float4 p4 = *(const float4*)(drow + 16);

#define STEP(S, PS)                                                           \
  {                                                                           \
    const float4 d = PS;                                                      \
    PS = *(const float4*)(drow + 4 * (hcb + S + 5));                          \
    const float* __restrict__ qc = qsh + (hcb + S) * (TQ * 4);                \
    _Pragma("unroll") for (int qi = 0; qi < TQ; ++qi) {                       \
      float4 qf = *(const float4*)(qc + qi * 4);                              \
      acc[qi] =                                                               \
          fmaf(qf.x, d.x, fmaf(qf.y, d.y, fmaf(qf.z, d.z, fmaf(qf.w, d.w, acc[qi])))); \
    }                                                                         \
  }
#define STEP_LAST(S, PS)                                                      \
  {                                                                           \
    const float4 d = PS;                                                      \
    const float* __restrict__ qc = qsh + (hcb + S) * (TQ * 4);                \
    _Pragma("unroll") for (int qi = 0; qi < TQ; ++qi) {                       \
      float4 qf = *(const float4*)(qc + qi * 4);                              \
      acc[qi] =                                                               \
          fmaf(qf.x, d.x, fmaf(qf.y, d.y, fmaf(qf.z, d.z, fmaf(qf.w, d.w, acc[qi])))); \
    }                                                                         \
  }
#pragma unroll 1
  for (int r = 0; r < 14; ++r) {
    const int hcb = r * 5;
    STEP(0, p0) STEP(1, p1) STEP(2, p2) STEP(3, p3) STEP(4, p4)
  }
  {
    const int hcb = 70;
    STEP_LAST(0, p0) STEP_LAST(1, p1) STEP_LAST(2, p2) STEP_LAST(3, p3) STEP_LAST(4, p4)
  }
#undef STEP
#undef STEP_LAST

  __syncthreads();
#pragma unroll
  for (int qi = 0; qi < TQ; ++qi) costmp[wave * 64 + lane][qi] = acc[qi] * invd;

  if (lane < TQ) {
    const int q = lane;
    float* tv = &topv[wave][q][0];
    float mn = tv[TOPK - 1];
    for (int tt = 0; tt < 64; ++tt) {
      float v = costmp[wave * 64 + tt][q];
      if (v > mn) {
        int p = TOPK - 1;
        while (p > 0 && tv[p - 1] < v) {
          tv[p] = tv[p - 1];
          --p;
        }
        tv[p] = v;
        mn = tv[TOPK - 1];
      }
    }
  }
  __syncthreads();

  if (tid < TQ) {
    const int q = tid;
    float* dst = &topv[0][q][0];
#pragma unroll
    for (int w = 1; w < 4; ++w) {
      for (int k = 0; k < TOPK; ++k) {
        float v = topv[w][q][k];
        if (v <= dst[TOPK - 1]) break;
        int p = TOPK - 1;
        while (p > 0 && dst[p - 1] < v) {
          dst[p] = dst[p - 1];
          --p;
        }
        dst[p] = v;
      }
    }
  }
  __syncthreads();

  for (int i = tid; i < TQ * TOPK; i += 256)
    partial[((size_t)(b * NCHUNK + chunk)) * (TQ * TOPK) + i] =
        topv[0][i / TOPK][i % TOPK];
}

// ---------------- Kernel 3: merge partials, FFW+tanh, gated softmax ----------------
__global__ __launch_bounds__(64) void finalize_kernel(
    const float* __restrict__ partial, const int* __restrict__ query,
    const float* __restrict__ qidf, const float* __restrict__ ffw_W,
    const float* __restrict__ ffw_b, const float* __restrict__ gates_W,
    const float* __restrict__ out_W, const float* __restrict__ out_b,
    float* __restrict__ out) {
  const int b = blockIdx.x;
  const int lane = (int)threadIdx.x;
  float ffw = 0.f;
  float logit = -3e38f;
  if (lane < TQ) {
    const int q = lane;
    int pos[NCHUNK];
#pragma unroll
    for (int c = 0; c < NCHUNK; ++c) pos[c] = 0;
    float s = 0.f;
    for (int k = 0; k < TOPK; ++k) {
      float best = -4.f;
      int bi = 0;
#pragma unroll
      for (int c = 0; c < NCHUNK; ++c) {
        float v = (pos[c] < TOPK)
                      ? partial[((size_t)(b * NCHUNK + c) * TQ + q) * TOPK + pos[c]]
                      : -4.f;
        if (v > best) {
          best = v;
          bi = c;
        }
      }
#pragma unroll
      for (int c = 0; c < NCHUNK; ++c)
        if (c == bi) pos[c]++;
      s += best * ffw_W[k];
    }
    ffw = tanhf(s + ffw_b[0]);
    int tok = query[b * TQ + q];
    logit = qidf[b * TQ + q] * gates_W[0] + (tok == 0 ? -1e7f : 0.f);
  }
  float m = logit;
#pragma unroll
  for (int off = 32; off; off >>= 1) m = fmaxf(m, __shfl_xor(m, off, 64));
  float e = expf(logit - m);
  float num = e * ffw;
  float den = e;
#pragma unroll
  for (int off = 32; off; off >>= 1) {
    num += __shfl_xor(num, off, 64);
    den += __shfl_xor(den, off, 64);
  }
  if (lane == 0) out[b] = (num / den) * out_W[0] + out_b[0];
}

extern "C" void kernel_launch(void* const* d_in, const int* in_sizes, int n_in,
                              void* d_out, int out_size, void* d_ws, size_t ws_size,
                              hipStream_t stream) {
  const int* doc = (const int*)d_in[0];
  const int* query = (const int*)d_in[1];
  const float* qidf = (const float*)d_in[2];
  const float* emb = (const float*)d_in[3];
  const float* ffw_W = (const float*)d_in[4];
  const float* ffw_b = (const float*)d_in[5];
  const float* gates_W = (const float*)d_in[6];
  const float* out_W = (const float*)d_in[7];
  const float* out_b = (const float*)d_in[8];
  float* out = (float*)d_out;

  char* ws = (char*)d_ws;
  float* invn = (float*)ws;  // 50048 floats = 200192 B (fallback path only)

  // MFMA-path layout (bytes): invn 200192 | qhi 2621440 | qlo 2621440 |
  // dhi 32000000 | dlo 32000000 | partial 5242880  => 74685952 total
  const size_t OFF_QHI = 200192;
  const size_t OFF_QLO = OFF_QHI + (size_t)NB * TQ * KP * 2;
  const size_t OFF_DHI = OFF_QLO + (size_t)NB * TQ * KP * 2;
  const size_t OFF_DLO = OFF_DHI + (size_t)VOCAB * KP * 2;
  const size_t OFF_PAR = OFF_DLO + (size_t)VOCAB * KP * 2;
  const size_t NEED = OFF_PAR + (size_t)NB * NCHUNK * TQ * TOPK * 4;

  if (ws_size >= NEED) {
    ushort* qhi = (ushort*)(ws + OFF_QHI);
    ushort* qlo = (ushort*)(ws + OFF_QLO);
    ushort* dhi = (ushort*)(ws + OFF_DHI);
    ushort* dlo = (ushort*)(ws + OFF_DLO);
    float* partial = (float*)(ws + OFF_PAR);
    dprep_kernel<<<(VOCAB + 3) / 4, 256, 0, stream>>>(emb, dhi, dlo);
    qprep2_kernel<<<NB, 256, 0, stream>>>(query, emb, qhi, qlo);
    dim3 grid(NCHUNK, NB);
    mfma_topk_kernel<<<grid, 256, 0, stream>>>(doc, qhi, qlo, dhi, dlo, partial);
    finalize_kernel<<<NB, 64, 0, stream>>>(partial, query, qidf, ffw_W, ffw_b,
                                           gates_W, out_W, out_b, out);
  } else {
    // R5 fallback: invn | qn_t (1228800 f) | partial (1310720 f) ~ 10.4 MB
    float* qn_t = invn + 50048;
    float* partial = qn_t + (size_t)NB * NHC * TQ * 4;
    rownorm_kernel<<<(VOCAB + 3) / 4, 256, 0, stream>>>(emb, invn);
    qprep_kernel<<<NB, 256, 0, stream>>>(query, emb, invn, qn_t);
    dim3 grid(NCHUNK, NB);
    cos_topk_kernel<<<grid, 256, 0, stream>>>(doc, emb, invn, qn_t, partial);
    finalize_kernel<<<NB, 64, 0, stream>>>(partial, query, qidf, ffw_W, ffw_b,
                                           gates_W, out_W, out_b, out);
  }
}

// Round 9
// 335.152 us; speedup vs baseline: 3.3095x; 1.0602x over previous
//
#include <hip/hip_runtime.h>
#include <math.h>

#define VOCAB 50000
#define EMB 300
#define NB 128
#define TQ 32
#define TD 4096
#define TOPK 20
#define KP 320               // padded K (10 x 32)
#define NCHUNK 16            // doc chunks (both paths)
#define NHC 75               // EMB/4 (fallback path)

typedef short short8 __attribute__((ext_vector_type(8)));
typedef float f32x4 __attribute__((ext_vector_type(4)));

// ---- RTNE float -> bf16 split helpers (device) ----
__device__ inline ushort bf16_rtne(float x) {
  unsigned u = __float_as_uint(x);
  unsigned r = u + 0x7fffu + ((u >> 16) & 1u);
  return (ushort)(r >> 16);
}

// ---------------- Kernel 1 (fallback only): per-row inverse norms ----------------
__global__ __launch_bounds__(256) void rownorm_kernel(const float* __restrict__ emb,
                                                      float* __restrict__ invn) {
  int row = blockIdx.x * 4 + (threadIdx.x >> 6);
  if (row >= VOCAB) return;
  int lane = threadIdx.x & 63;
  float s = 0.f;
  for (int h = lane; h < EMB; h += 64) {
    float v = emb[row * EMB + h];
    s += v * v;
  }
#pragma unroll
  for (int off = 32; off; off >>= 1) s += __shfl_xor(s, off, 64);
  if (lane == 0) invn[row] = 1.0f / fmaxf(sqrtf(s), 1e-8f);
}

// ---------------- MFMA prep: fused norm + split + pad (doc table) ----------------
__global__ __launch_bounds__(256) void dprep_kernel(const float* __restrict__ emb,
                                                    ushort* __restrict__ dhi,
                                                    ushort* __restrict__ dlo) {
  int row = blockIdx.x * 4 + (threadIdx.x >> 6);
  if (row >= VOCAB) return;
  int lane = threadIdx.x & 63;
  float v[5];
  float s = 0.f;
#pragma unroll
  for (int j = 0; j < 5; ++j) {
    int k = j * 64 + lane;
    float x = (k < EMB) ? emb[(size_t)row * EMB + k] : 0.f;
    v[j] = x;
    s += x * x;
  }
#pragma unroll
  for (int off = 32; off; off >>= 1) s += __shfl_xor(s, off, 64);
  float inv = 1.0f / fmaxf(sqrtf(s), 1e-8f);
#pragma unroll
  for (int j = 0; j < 5; ++j) {
    int k = j * 64 + lane;
    float x = v[j] * inv;
    ushort h = bf16_rtne(x);
    float hf = __uint_as_float((unsigned)h << 16);
    ushort l = bf16_rtne(x - hf);
    dhi[(size_t)row * KP + k] = h;
    dlo[(size_t)row * KP + k] = l;
  }
}

__global__ __launch_bounds__(256) void qprep2_kernel(const int* __restrict__ query,
                                                     const float* __restrict__ emb,
                                                     ushort* __restrict__ qhi,
                                                     ushort* __restrict__ qlo) {
  const int b = blockIdx.x;
  const int wave = (int)threadIdx.x >> 6;
  const int lane = (int)threadIdx.x & 63;
#pragma unroll 1
  for (int q = wave; q < TQ; q += 4) {
    int tok = query[b * TQ + q];
    float v[5];
    float s = 0.f;
#pragma unroll
    for (int j = 0; j < 5; ++j) {
      int k = j * 64 + lane;
      float x = (k < EMB) ? emb[(size_t)tok * EMB + k] : 0.f;
      v[j] = x;
      s += x * x;
    }
#pragma unroll
    for (int off = 32; off; off >>= 1) s += __shfl_xor(s, off, 64);
    float inv = 1.0f / fmaxf(sqrtf(s), 1e-8f);
#pragma unroll
    for (int j = 0; j < 5; ++j) {
      int k = j * 64 + lane;
      float x = v[j] * inv;
      ushort h = bf16_rtne(x);
      float hf = __uint_as_float((unsigned)h << 16);
      ushort l = bf16_rtne(x - hf);
      qhi[(size_t)(b * TQ + q) * KP + k] = h;
      qlo[(size_t)(b * TQ + q) * KP + k] = l;
    }
  }
}

// ---------------- MFMA main: asm-pipelined gathers, counted vmcnt ----------------
// grid (16, NB), block 256 (4 waves). Wave: 32q x 64 tokens, 8 named f32x4 acc.
// Loads are volatile asm global_load_dwordx4 (compiler can't sink/reuse regs,
// inserts no waits); hand-scheduled: always 24 in flight, vmcnt(12) before
// each MFMA cluster (never drain to 0 until the last step). K-step advance is
// a literal offset: immediate -> zero addr VALU in the pipeline.
__global__ __launch_bounds__(256, 3) void mfma_topk_kernel(
    const int* __restrict__ doc, const ushort* __restrict__ qhi,
    const ushort* __restrict__ qlo, const ushort* __restrict__ dhi,
    const ushort* __restrict__ dlo, float* __restrict__ partial) {
  __shared__ float costmp[4][64][33];  // [wave][token][q], pad 33
  __shared__ float topv[4][TQ][21];

  const int b = blockIdx.y;
  const int chunk = blockIdx.x;
  const int tid = (int)threadIdx.x;
  const int wave = tid >> 6;
  const int lane = tid & 63;
  const int c = lane & 15;
  const int kg = lane >> 4;

  const int tbase = b * TD + chunk * 256 + wave * 64;
  const ushort* pdh0 = dhi + (size_t)doc[tbase + 0 * 16 + c] * KP + kg * 8;
  const ushort* pdh1 = dhi + (size_t)doc[tbase + 1 * 16 + c] * KP + kg * 8;
  const ushort* pdh2 = dhi + (size_t)doc[tbase + 2 * 16 + c] * KP + kg * 8;
  const ushort* pdh3 = dhi + (size_t)doc[tbase + 3 * 16 + c] * KP + kg * 8;
  const ushort* pdl0 = dlo + (size_t)doc[tbase + 0 * 16 + c] * KP + kg * 8;
  const ushort* pdl1 = dlo + (size_t)doc[tbase + 1 * 16 + c] * KP + kg * 8;
  const ushort* pdl2 = dlo + (size_t)doc[tbase + 2 * 16 + c] * KP + kg * 8;
  const ushort* pdl3 = dlo + (size_t)doc[tbase + 3 * 16 + c] * KP + kg * 8;
  const ushort* pqh0 = qhi + (size_t)(b * TQ + c) * KP + kg * 8;
  const ushort* pqh1 = qhi + (size_t)(b * TQ + 16 + c) * KP + kg * 8;
  const ushort* pql0 = qlo + (size_t)(b * TQ + c) * KP + kg * 8;
  const ushort* pql1 = qlo + (size_t)(b * TQ + 16 + c) * KP + kg * 8;

  f32x4 a00 = {0.f, 0.f, 0.f, 0.f}, a01 = a00, a02 = a00, a03 = a00;
  f32x4 a10 = a00, a11 = a00, a12 = a00, a13 = a00;

  short8 ah0P, ah1P, al0P, al1P, bh0P, bh1P, bh2P, bh3P, bl0P, bl1P, bl2P, bl3P;
  short8 ah0Q, ah1Q, al0Q, al1Q, bh0Q, bh1Q, bh2Q, bh3Q, bl0Q, bl1Q, bl2Q, bl3Q;

#define STR2(x) #x
#define STR(x) STR2(x)
#define LD1(DST, PTR, OFFB)                                              \
  asm volatile("global_load_dwordx4 %0, %1, off offset:" STR(OFFB)       \
               : "=v"(DST)                                               \
               : "v"(PTR));
#define LOADSET(S, OFFB)                                                 \
  LD1(ah0##S, pqh0, OFFB) LD1(ah1##S, pqh1, OFFB)                        \
  LD1(al0##S, pql0, OFFB) LD1(al1##S, pql1, OFFB)                        \
  LD1(bh0##S, pdh0, OFFB) LD1(bh1##S, pdh1, OFFB)                        \
  LD1(bh2##S, pdh2, OFFB) LD1(bh3##S, pdh3, OFFB)                        \
  LD1(bl0##S, pdl0, OFFB) LD1(bl1##S, pdl1, OFFB)                        \
  LD1(bl2##S, pdl2, OFFB) LD1(bl3##S, pdl3, OFFB)

#define WAIT12                                        \
  asm volatile("s_waitcnt vmcnt(12)" ::: "memory");   \
  __builtin_amdgcn_sched_barrier(0);
#define WAIT0                                         \
  asm volatile("s_waitcnt vmcnt(0)" ::: "memory");    \
  __builtin_amdgcn_sched_barrier(0);

#define MM3(ACC, AH, AL, BH, BL)                                          \
  ACC = __builtin_amdgcn_mfma_f32_16x16x32_bf16(AH, BH, ACC, 0, 0, 0);    \
  ACC = __builtin_amdgcn_mfma_f32_16x16x32_bf16(AH, BL, ACC, 0, 0, 0);    \
  ACC = __builtin_amdgcn_mfma_f32_16x16x32_bf16(AL, BH, ACC, 0, 0, 0);

#define MMALL(S)                           \
  MM3(a00, ah0##S, al0##S, bh0##S, bl0##S) \
  MM3(a01, ah0##S, al0##S, bh1##S, bl1##S) \
  MM3(a02, ah0##S, al0##S, bh2##S, bl2##S) \
  MM3(a03, ah0##S, al0##S, bh3##S, bl3##S) \
  MM3(a10, ah1##S, al1##S, bh0##S, bl0##S) \
  MM3(a11, ah1##S, al1##S, bh1##S, bl1##S) \
  MM3(a12, ah1##S, al1##S, bh2##S, bl2##S) \
  MM3(a13, ah1##S, al1##S, bh3##S, bl3##S)

  // ks: byte offset = ks*64; 10 steps (KP/32). Always 24 loads in flight.
  LOADSET(P, 0)
  LOADSET(Q, 64)
  WAIT12 MMALL(P) LOADSET(P, 128)
  WAIT12 MMALL(Q) LOADSET(Q, 192)
  WAIT12 MMALL(P) LOADSET(P, 256)
  WAIT12 MMALL(Q) LOADSET(Q, 320)
  WAIT12 MMALL(P) LOADSET(P, 384)
  WAIT12 MMALL(Q) LOADSET(Q, 448)
  WAIT12 MMALL(P) LOADSET(P, 512)
  WAIT12 MMALL(Q) LOADSET(Q, 576)
  WAIT12 MMALL(P)
  WAIT0  MMALL(Q)

#undef LOADSET
#undef LD1
#undef WAIT12
#undef WAIT0
#undef MM3
#undef MMALL
#undef STR
#undef STR2

  // scatter C tiles to costmp: C col=lane&15 (token), row=kg*4+reg (q in tile)
#define WT(ACC, M, NT)                                        \
  {                                                           \
    float* dst = &costmp[wave][NT * 16 + c][M * 16 + kg * 4]; \
    dst[0] = ACC[0]; dst[1] = ACC[1];                         \
    dst[2] = ACC[2]; dst[3] = ACC[3];                         \
  }
  WT(a00, 0, 0) WT(a01, 0, 1) WT(a02, 0, 2) WT(a03, 0, 3)
  WT(a10, 1, 0) WT(a11, 1, 1) WT(a12, 1, 2) WT(a13, 1, 3)
#undef WT

  // per-wave top-20 scan over this wave's 64 tokens (R5-proven)
  if (lane < TQ) {
    const int q = lane;
    float* tv = &topv[wave][q][0];
#pragma unroll
    for (int k = 0; k < TOPK; ++k) tv[k] = -2.0f;
    float mn = -2.0f;
    for (int tt = 0; tt < 64; ++tt) {
      float v = costmp[wave][tt][q];
      if (v > mn) {
        int p = TOPK - 1;
        while (p > 0 && tv[p - 1] < v) {
          tv[p] = tv[p - 1];
          --p;
        }
        tv[p] = v;
        mn = tv[TOPK - 1];
      }
    }
  }
  __syncthreads();

  // combine 4 wave lists into topv[0]
  if (tid < TQ) {
    const int q = tid;
    float* dst = &topv[0][q][0];
#pragma unroll
    for (int w = 1; w < 4; ++w) {
      for (int k = 0; k < TOPK; ++k) {
        float v = topv[w][q][k];
        if (v <= dst[TOPK - 1]) break;
        int p = TOPK - 1;
        while (p > 0 && dst[p - 1] < v) {
          dst[p] = dst[p - 1];
          --p;
        }
        dst[p] = v;
      }
    }
  }
  __syncthreads();

  for (int i = tid; i < TQ * TOPK; i += 256)
    partial[((size_t)(b * NCHUNK + chunk)) * (TQ * TOPK) + i] =
        topv[0][i / TOPK][i % TOPK];
}

// ---------------- Fallback path (R5, proven 476us): fp32 VALU ----------------
__global__ __launch_bounds__(256) void qprep_kernel(const int* __restrict__ query,
                                                    const float* __restrict__ emb,
                                                    const float* __restrict__ invn,
                                                    float* __restrict__ qn_t) {
  const int b = blockIdx.x;
  for (int i = (int)threadIdx.x; i < NHC * TQ; i += 256) {
    int hc = i >> 5, q = i & 31;
    int tok = query[b * TQ + q];
    float inv = invn[tok];
    float4 v = *(const float4*)(emb + (size_t)tok * EMB + hc * 4);
    float4 o;
    o.x = v.x * inv; o.y = v.y * inv; o.z = v.z * inv; o.w = v.w * inv;
    *(float4*)(qn_t + (((size_t)b * NHC + hc) * TQ + q) * 4) = o;
  }
}

__global__ __launch_bounds__(256, 3) void cos_topk_kernel(
    const int* __restrict__ doc, const float* __restrict__ emb,
    const float* __restrict__ invn, const float* __restrict__ qn_t,
    float* __restrict__ partial) {
  __shared__ __align__(16) float smem[9600];
  __shared__ float topv[4][TQ][21];
  float* qsh = smem;
  float (*costmp)[33] = (float (*)[33])smem;

  const int b = blockIdx.y;
  const int chunk = blockIdx.x;
  const int tid = (int)threadIdx.x;
  const int wave = tid >> 6;
  const int lane = tid & 63;

  {
    const float4* src = (const float4*)(qn_t + (size_t)b * (NHC * TQ * 4));
    float4* dst = (float4*)qsh;
    for (int i = tid; i < NHC * TQ; i += 256) dst[i] = src[i];
  }
  if (lane < TQ) {
#pragma unroll
    for (int k = 0; k < TOPK; ++k) topv[wave][lane][k] = -2.0f;
  }
  __syncthreads();

  const int tok = doc[b * TD + chunk * 256 + tid];
  const float invd = invn[tok];
  const float* __restrict__ drow = emb + (size_t)tok * EMB;

  float acc[TQ];
#pragma unroll
  for (int qi = 0; qi < TQ; ++qi) acc[qi] = 0.f;

  float4 p0 = *(const float4*)(drow + 0);
  float4 p1 = *(const float4*)(drow + 4);
  float4 p2 = *(const float4*)(drow + 8);
  float4 p3 = *(const float4*)(drow + 12);
  float4 p4 = *(const float4*)(drow + 16);

#define STEP(S, PS)                                                           \
  {                                                                           \
    const float4 d = PS;                                                      \
    PS = *(const float4*)(drow + 4 * (hcb + S + 5));                          \
    const float* __restrict__ qc = qsh + (hcb + S) * (TQ * 4);                \
    _Pragma("unroll") for (int qi = 0; qi < TQ; ++qi) {                       \
      float4 qf = *(const float4*)(qc + qi * 4);                              \
      acc[qi] =                                                               \
          fmaf(qf.x, d.x, fmaf(qf.y, d.y, fmaf(qf.z, d.z, fmaf(qf.w, d.w, acc[qi])))); \
    }                                                                         \
  }
#define STEP_LAST(S, PS)                                                      \
  {                                                                           \
    const float4 d = PS;                                                      \
    const float* __restrict__ qc = qsh + (hcb + S) * (TQ * 4);                \
    _Pragma("unroll") for (int qi = 0; qi < TQ; ++qi) {                       \
      float4 qf = *(const float4*)(qc + qi * 4);                              \
      acc[qi] =                                                               \
          fmaf(qf.x, d.x, fmaf(qf.y, d.y, fmaf(qf.z, d.z, fmaf(qf.w, d.w, acc[qi])))); \
    }                                                                         \
  }
#pragma unroll 1
  for (int r = 0; r < 14; ++r) {
    const int hcb = r * 5;
    STEP(0, p0) STEP(1, p1) STEP(2, p2) STEP(3, p3) STEP(4, p4)
  }
  {
    const int hcb = 70;
    STEP_LAST(0, p0) STEP_LAST(1, p1) STEP_LAST(2, p2) STEP_LAST(3, p3) STEP_LAST(4, p4)
  }
#undef STEP
#undef STEP_LAST

  __syncthreads();
#pragma unroll
  for (int qi = 0; qi < TQ; ++qi) costmp[wave * 64 + lane][qi] = acc[qi] * invd;

  if (lane < TQ) {
    const int q = lane;
    float* tv = &topv[wave][q][0];
    float mn = tv[TOPK - 1];
    for (int tt = 0; tt < 64; ++tt) {
      float v = costmp[wave * 64 + tt][q];
      if (v > mn) {
        int p = TOPK - 1;
        while (p > 0 && tv[p - 1] < v) {
          tv[p] = tv[p - 1];
          --p;
        }
        tv[p] = v;
        mn = tv[TOPK - 1];
      }
    }
  }
  __syncthreads();

  if (tid < TQ) {
    const int q = tid;
    float* dst = &topv[0][q][0];
#pragma unroll
    for (int w = 1; w < 4; ++w) {
      for (int k = 0; k < TOPK; ++k) {
        float v = topv[w][q][k];
        if (v <= dst[TOPK - 1]) break;
        int p = TOPK - 1;
        while (p > 0 && dst[p - 1] < v) {
          dst[p] = dst[p - 1];
          --p;
        }
        dst[p] = v;
      }
    }
  }
  __syncthreads();

  for (int i = tid; i < TQ * TOPK; i += 256)
    partial[((size_t)(b * NCHUNK + chunk)) * (TQ * TOPK) + i] =
        topv[0][i / TOPK][i % TOPK];
}

// ---------------- Kernel 3: merge partials, FFW+tanh, gated softmax ----------------
__global__ __launch_bounds__(64) void finalize_kernel(
    const float* __restrict__ partial, const int* __restrict__ query,
    const float* __restrict__ qidf, const float* __restrict__ ffw_W,
    const float* __restrict__ ffw_b, const float* __restrict__ gates_W,
    const float* __restrict__ out_W, const float* __restrict__ out_b,
    float* __restrict__ out) {
  const int b = blockIdx.x;
  const int lane = (int)threadIdx.x;
  float ffw = 0.f;
  float logit = -3e38f;
  if (lane < TQ) {
    const int q = lane;
    int pos[NCHUNK];
#pragma unroll
    for (int c = 0; c < NCHUNK; ++c) pos[c] = 0;
    float s = 0.f;
    for (int k = 0; k < TOPK; ++k) {
      float best = -4.f;
      int bi = 0;
#pragma unroll
      for (int c = 0; c < NCHUNK; ++c) {
        float v = (pos[c] < TOPK)
                      ? partial[((size_t)(b * NCHUNK + c) * TQ + q) * TOPK + pos[c]]
                      : -4.f;
        if (v > best) {
          best = v;
          bi = c;
        }
      }
#pragma unroll
      for (int c = 0; c < NCHUNK; ++c)
        if (c == bi) pos[c]++;
      s += best * ffw_W[k];
    }
    ffw = tanhf(s + ffw_b[0]);
    int tok = query[b * TQ + q];
    logit = qidf[b * TQ + q] * gates_W[0] + (tok == 0 ? -1e7f : 0.f);
  }
  float m = logit;
#pragma unroll
  for (int off = 32; off; off >>= 1) m = fmaxf(m, __shfl_xor(m, off, 64));
  float e = expf(logit - m);
  float num = e * ffw;
  float den = e;
#pragma unroll
  for (int off = 32; off; off >>= 1) {
    num += __shfl_xor(num, off, 64);
    den += __shfl_xor(den, off, 64);
  }
  if (lane == 0) out[b] = (num / den) * out_W[0] + out_b[0];
}

extern "C" void kernel_launch(void* const* d_in, const int* in_sizes, int n_in,
                              void* d_out, int out_size, void* d_ws, size_t ws_size,
                              hipStream_t stream) {
  const int* doc = (const int*)d_in[0];
  const int* query = (const int*)d_in[1];
  const float* qidf = (const float*)d_in[2];
  const float* emb = (const float*)d_in[3];
  const float* ffw_W = (const float*)d_in[4];
  const float* ffw_b = (const float*)d_in[5];
  const float* gates_W = (const float*)d_in[6];
  const float* out_W = (const float*)d_in[7];
  const float* out_b = (const float*)d_in[8];
  float* out = (float*)d_out;

  char* ws = (char*)d_ws;
  float* invn = (float*)ws;  // 50048 floats = 200192 B (fallback path only)

  // MFMA-path layout (bytes): invn 200192 | qhi 2621440 | qlo 2621440 |
  // dhi 32000000 | dlo 32000000 | partial 5242880  => 74685952 total
  const size_t OFF_QHI = 200192;
  const size_t OFF_QLO = OFF_QHI + (size_t)NB * TQ * KP * 2;
  const size_t OFF_DHI = OFF_QLO + (size_t)NB * TQ * KP * 2;
  const size_t OFF_DLO = OFF_DHI + (size_t)VOCAB * KP * 2;
  const size_t OFF_PAR = OFF_DLO + (size_t)VOCAB * KP * 2;
  const size_t NEED = OFF_PAR + (size_t)NB * NCHUNK * TQ * TOPK * 4;

  if (ws_size >= NEED) {
    ushort* qhi = (ushort*)(ws + OFF_QHI);
    ushort* qlo = (ushort*)(ws + OFF_QLO);
    ushort* dhi = (ushort*)(ws + OFF_DHI);
    ushort* dlo = (ushort*)(ws + OFF_DLO);
    float* partial = (float*)(ws + OFF_PAR);
    dprep_kernel<<<(VOCAB + 3) / 4, 256, 0, stream>>>(emb, dhi, dlo);
    qprep2_kernel<<<NB, 256, 0, stream>>>(query, emb, qhi, qlo);
    dim3 grid(NCHUNK, NB);
    mfma_topk_kernel<<<grid, 256, 0, stream>>>(doc, qhi, qlo, dhi, dlo, partial);
    finalize_kernel<<<NB, 64, 0, stream>>>(partial, query, qidf, ffw_W, ffw_b,
                                           gates_W, out_W, out_b, out);
  } else {
    // R5 fallback: invn | qn_t (1228800 f) | partial (1310720 f) ~ 10.4 MB
    float* qn_t = invn + 50048;
    float* partial = qn_t + (size_t)NB * NHC * TQ * 4;
    rownorm_kernel<<<(VOCAB + 3) / 4, 256, 0, stream>>>(emb, invn);
    qprep_kernel<<<NB, 256, 0, stream>>>(query, emb, invn, qn_t);
    dim3 grid(NCHUNK, NB);
    cos_topk_kernel<<<grid, 256, 0, stream>>>(doc, emb, invn, qn_t, partial);
    finalize_kernel<<<NB, 64, 0, stream>>>(partial, query, qidf, ffw_W, ffw_b,
                                           gates_W, out_W, out_b, out);
  }
}

// Round 11
// 298.111 us; speedup vs baseline: 3.7207x; 1.1243x over previous
//
#include <hip/hip_runtime.h>
#include <math.h>

#define VOCAB 50000
#define EMB 300
#define NB 128
#define TQ 32
#define TD 4096
#define TOPK 20
#define KP 320               // padded K (10 x 32)
#define NCHUNK 16            // doc chunks (both paths)
#define NHC 75               // EMB/4 (fallback path)
#define QSTRIDE 656          // padded LDS row stride (bytes) for q slab

typedef short short8 __attribute__((ext_vector_type(8)));
typedef float f32x4 __attribute__((ext_vector_type(4)));

// ---- RTNE float -> bf16 helper ----
__device__ inline ushort bf16_rtne(float x) {
  unsigned u = __float_as_uint(x);
  unsigned r = u + 0x7fffu + ((u >> 16) & 1u);
  return (ushort)(r >> 16);
}

// ---------------- Kernel 1 (fallback only): per-row inverse norms ----------------
__global__ __launch_bounds__(256) void rownorm_kernel(const float* __restrict__ emb,
                                                      float* __restrict__ invn) {
  int row = blockIdx.x * 4 + (threadIdx.x >> 6);
  if (row >= VOCAB) return;
  int lane = threadIdx.x & 63;
  float s = 0.f;
  for (int h = lane; h < EMB; h += 64) {
    float v = emb[row * EMB + h];
    s += v * v;
  }
#pragma unroll
  for (int off = 32; off; off >>= 1) s += __shfl_xor(s, off, 64);
  if (lane == 0) invn[row] = 1.0f / fmaxf(sqrtf(s), 1e-8f);
}

// ---------------- MFMA prep: fused norm + bf16(hi) + pad (doc table) ----------------
__global__ __launch_bounds__(256) void dprep_kernel(const float* __restrict__ emb,
                                                    ushort* __restrict__ dhi) {
  int row = blockIdx.x * 4 + (threadIdx.x >> 6);
  if (row >= VOCAB) return;
  int lane = threadIdx.x & 63;
  float v[5];
  float s = 0.f;
#pragma unroll
  for (int j = 0; j < 5; ++j) {
    int k = j * 64 + lane;
    float x = (k < EMB) ? emb[(size_t)row * EMB + k] : 0.f;
    v[j] = x;
    s += x * x;
  }
#pragma unroll
  for (int off = 32; off; off >>= 1) s += __shfl_xor(s, off, 64);
  float inv = 1.0f / fmaxf(sqrtf(s), 1e-8f);
#pragma unroll
  for (int j = 0; j < 5; ++j) {
    int k = j * 64 + lane;
    dhi[(size_t)row * KP + k] = bf16_rtne(v[j] * inv);
  }
}

__global__ __launch_bounds__(256) void qprep2_kernel(const int* __restrict__ query,
                                                     const float* __restrict__ emb,
                                                     ushort* __restrict__ qhi) {
  const int b = blockIdx.x;
  const int wave = (int)threadIdx.x >> 6;
  const int lane = (int)threadIdx.x & 63;
#pragma unroll 1
  for (int q = wave; q < TQ; q += 4) {
    int tok = query[b * TQ + q];
    float v[5];
    float s = 0.f;
#pragma unroll
    for (int j = 0; j < 5; ++j) {
      int k = j * 64 + lane;
      float x = (k < EMB) ? emb[(size_t)tok * EMB + k] : 0.f;
      v[j] = x;
      s += x * x;
    }
#pragma unroll
    for (int off = 32; off; off >>= 1) s += __shfl_xor(s, off, 64);
    float inv = 1.0f / fmaxf(sqrtf(s), 1e-8f);
#pragma unroll
    for (int j = 0; j < 5; ++j) {
      int k = j * 64 + lane;
      qhi[(size_t)(b * TQ + q) * KP + k] = bf16_rtne(v[j] * inv);
    }
  }
}

// ---------------- MFMA main: hi-only, LDS q-slab, depth-5 doc pipeline ----------------
// grid (16, NB), block 256 (4 waves). Wave: 32q x 64 tokens, 8 f32x4 acc.
// Doc frag loads = volatile asm global_load_dwordx4, 5 sets x 4 loads, steady
// state 20 outstanding, s_waitcnt vmcnt(16) per step (drain only in tail).
// Q frags come from a 21KB LDS slab (stride 656B -> conflict-free b128),
// staged once per block: q global traffic drops 327->41 MB; lo tables gone.
__global__ __launch_bounds__(256, 3) void mfma_topk_kernel(
    const int* __restrict__ doc, const ushort* __restrict__ qhi,
    const ushort* __restrict__ dhi, float* __restrict__ partial) {
  __shared__ __align__(16) char smem[33792];  // qsh (20992B), later costmp
  __shared__ float topv[4][TQ][21];

  float (*costmp)[64][33] = (float (*)[64][33])smem;  // [wave][token][q]

  const int b = blockIdx.y;
  const int chunk = blockIdx.x;
  const int tid = (int)threadIdx.x;
  const int wave = tid >> 6;
  const int lane = tid & 63;
  const int c = lane & 15;
  const int kg = lane >> 4;

  // stage this batch's q-hi slab into LDS (coalesced short8, padded stride)
  {
    const ushort* qsrc = qhi + (size_t)b * TQ * KP;
    for (int i = tid; i < TQ * (KP / 8); i += 256) {
      int row = i / (KP / 8), j = i - row * (KP / 8);
      *(short8*)(smem + row * QSTRIDE + j * 16) =
          *(const short8*)(qsrc + row * KP + j * 8);
    }
  }
  __syncthreads();  // qsh ready

  const int tbase = b * TD + chunk * 256 + wave * 64;
  const ushort* pdh0 = dhi + (size_t)doc[tbase + 0 * 16 + c] * KP + kg * 8;
  const ushort* pdh1 = dhi + (size_t)doc[tbase + 1 * 16 + c] * KP + kg * 8;
  const ushort* pdh2 = dhi + (size_t)doc[tbase + 2 * 16 + c] * KP + kg * 8;
  const ushort* pdh3 = dhi + (size_t)doc[tbase + 3 * 16 + c] * KP + kg * 8;
  const char* qb0 = smem + c * QSTRIDE + kg * 16;
  const char* qb1 = smem + (16 + c) * QSTRIDE + kg * 16;

  f32x4 a00 = {0.f, 0.f, 0.f, 0.f}, a01 = a00, a02 = a00, a03 = a00;
  f32x4 a10 = a00, a11 = a00, a12 = a00, a13 = a00;

  short8 bh0A, bh1A, bh2A, bh3A, bh0B, bh1B, bh2B, bh3B, bh0C, bh1C, bh2C,
      bh3C, bh0D, bh1D, bh2D, bh3D, bh0E, bh1E, bh2E, bh3E;

#define STR2(x) #x
#define STR(x) STR2(x)
#define LD1(DST, PTR, OFFB)                                        \
  asm volatile("global_load_dwordx4 %0, %1, off offset:" STR(OFFB) \
               : "=v"(DST)                                         \
               : "v"(PTR));
#define LOADSET(S, OFFB)                                  \
  LD1(bh0##S, pdh0, OFFB) LD1(bh1##S, pdh1, OFFB)         \
  LD1(bh2##S, pdh2, OFFB) LD1(bh3##S, pdh3, OFFB)

#define MFMA_BF16 __builtin_amdgcn_mfma_f32_16x16x32_bf16
#define KSTEP_BODY(S, KS)                                        \
  {                                                              \
    const short8 ah0 = *(const short8*)(qb0 + (KS) * 64);        \
    const short8 ah1 = *(const short8*)(qb1 + (KS) * 64);        \
    a00 = MFMA_BF16(ah0, bh0##S, a00, 0, 0, 0);                  \
    a01 = MFMA_BF16(ah0, bh1##S, a01, 0, 0, 0);                  \
    a02 = MFMA_BF16(ah0, bh2##S, a02, 0, 0, 0);                  \
    a03 = MFMA_BF16(ah0, bh3##S, a03, 0, 0, 0);                  \
    a10 = MFMA_BF16(ah1, bh0##S, a10, 0, 0, 0);                  \
    a11 = MFMA_BF16(ah1, bh1##S, a11, 0, 0, 0);                  \
    a12 = MFMA_BF16(ah1, bh2##S, a12, 0, 0, 0);                  \
    a13 = MFMA_BF16(ah1, bh3##S, a13, 0, 0, 0);                  \
  }
#define WAITC(N)                                            \
  asm volatile("s_waitcnt vmcnt(" STR(N) ")" ::: "memory"); \
  __builtin_amdgcn_sched_barrier(0);

#define KSTEP_R(S, KS, WN, RKS) WAITC(WN) KSTEP_BODY(S, KS) LOADSET(S, RKS)
#define KSTEP_N(S, KS, WN) WAITC(WN) KSTEP_BODY(S, KS)

  // prologue: fill depth-5 pipeline (20 loads in flight)
  LOADSET(A, 0)
  LOADSET(B, 64)
  LOADSET(C, 128)
  LOADSET(D, 192)
  LOADSET(E, 256)
  // 10 K-steps; byte offset = ks*64
  KSTEP_R(A, 0, 16, 320)
  KSTEP_R(B, 1, 16, 384)
  KSTEP_R(C, 2, 16, 448)
  KSTEP_R(D, 3, 16, 512)
  KSTEP_R(E, 4, 16, 576)
  KSTEP_N(A, 5, 16)
  KSTEP_N(B, 6, 12)
  KSTEP_N(C, 7, 8)
  KSTEP_N(D, 8, 4)
  KSTEP_N(E, 9, 0)

#undef KSTEP_R
#undef KSTEP_N
#undef WAITC
#undef KSTEP_BODY
#undef MFMA_BF16
#undef LOADSET
#undef LD1
#undef STR
#undef STR2

  __syncthreads();  // all waves done reading qsh; safe to overwrite with costmp

  // scatter C tiles: C col=lane&15 (token), row=kg*4+reg (q in tile)
#define WT(ACC, M, NT)                                            \
  {                                                               \
    float* dst = &costmp[wave][NT * 16 + c][M * 16 + kg * 4];     \
    dst[0] = ACC[0]; dst[1] = ACC[1];                             \
    dst[2] = ACC[2]; dst[3] = ACC[3];                             \
  }
  WT(a00, 0, 0) WT(a01, 0, 1) WT(a02, 0, 2) WT(a03, 0, 3)
  WT(a10, 1, 0) WT(a11, 1, 1) WT(a12, 1, 2) WT(a13, 1, 3)
#undef WT

  // per-wave top-20 scan over this wave's 64 tokens (R5-proven)
  if (lane < TQ) {
    const int q = lane;
    float* tv = &topv[wave][q][0];
#pragma unroll
    for (int k = 0; k < TOPK; ++k) tv[k] = -2.0f;
    float mn = -2.0f;
    for (int tt = 0; tt < 64; ++tt) {
      float v = costmp[wave][tt][q];
      if (v > mn) {
        int p = TOPK - 1;
        while (p > 0 && tv[p - 1] < v) {
          tv[p] = tv[p - 1];
          --p;
        }
        tv[p] = v;
        mn = tv[TOPK - 1];
      }
    }
  }
  __syncthreads();

  // combine 4 wave lists into topv[0]
  if (tid < TQ) {
    const int q = tid;
    float* dst = &topv[0][q][0];
#pragma unroll
    for (int w = 1; w < 4; ++w) {
      for (int k = 0; k < TOPK; ++k) {
        float v = topv[w][q][k];
        if (v <= dst[TOPK - 1]) break;
        int p = TOPK - 1;
        while (p > 0 && dst[p - 1] < v) {
          dst[p] = dst[p - 1];
          --p;
        }
        dst[p] = v;
      }
    }
  }
  __syncthreads();

  for (int i = tid; i < TQ * TOPK; i += 256)
    partial[((size_t)(b * NCHUNK + chunk)) * (TQ * TOPK) + i] =
        topv[0][i / TOPK][i % TOPK];
}

// ---------------- Fallback path (R5, proven 476us): fp32 VALU ----------------
__global__ __launch_bounds__(256) void qprep_kernel(const int* __restrict__ query,
                                                    const float* __restrict__ emb,
                                                    const float* __restrict__ invn,
                                                    float* __restrict__ qn_t) {
  const int b = blockIdx.x;
  for (int i = (int)threadIdx.x; i < NHC * TQ; i += 256) {
    int hc = i >> 5, q = i & 31;
    int tok = query[b * TQ + q];
    float inv = invn[tok];
    float4 v = *(const float4*)(emb + (size_t)tok * EMB + hc * 4);
    float4 o;
    o.x = v.x * inv; o.y = v.y * inv; o.z = v.z * inv; o.w = v.w * inv;
    *(float4*)(qn_t + (((size_t)b * NHC + hc) * TQ + q) * 4) = o;
  }
}

__global__ __launch_bounds__(256, 3) void cos_topk_kernel(
    const int* __restrict__ doc, const float* __restrict__ emb,
    const float* __restrict__ invn, const float* __restrict__ qn_t,
    float* __restrict__ partial) {
  __shared__ __align__(16) float smem_f[9600];
  __shared__ float topv[4][TQ][21];
  float* qsh = smem_f;
  float (*costmp)[33] = (float (*)[33])smem_f;

  const int b = blockIdx.y;
  const int chunk = blockIdx.x;
  const int tid = (int)threadIdx.x;
  const int wave = tid >> 6;
  const int lane = tid & 63;

  {
    const float4* src = (const float4*)(qn_t + (size_t)b * (NHC * TQ * 4));
    float4* dst = (float4*)qsh;
    for (int i = tid; i < NHC * TQ; i += 256) dst[i] = src[i];
  }
  if (lane < TQ) {
#pragma unroll
    for (int k = 0; k < TOPK; ++k) topv[wave][lane][k] = -2.0f;
  }
  __syncthreads();

  const int tok = doc[b * TD + chunk * 256 + tid];
  const float invd = invn[tok];
  const float* __restrict__ drow = emb + (size_t)tok * EMB;

  float acc[TQ];
#pragma unroll
  for (int qi = 0; qi < TQ; ++qi) acc[qi] = 0.f;

  float4 p0 = *(const float4*)(drow + 0);
  float4 p1 = *(const float4*)(drow + 4);
  float4 p2 = *(const float4*)(drow + 8);
  float4 p3 = *(const float4*)(drow + 12);
  float4 p4 = *(const float4*)(drow + 16);

#define STEP(S, PS)                                                           \
  {                                                                           \
    const float4 d = PS;                                                      \
    PS = *(const float4*)(drow + 4 * (hcb + S + 5));                          \
    const float* __restrict__ qc = qsh + (hcb + S) * (TQ * 4);                \
    _Pragma("unroll") for (int qi = 0; qi < TQ; ++qi) {                       \
      float4 qf = *(const float4*)(qc + qi * 4);                              \
      acc[qi] =                                                               \
          fmaf(qf.x, d.x, fmaf(qf.y, d.y, fmaf(qf.z, d.z, fmaf(qf.w, d.w, acc[qi])))); \
    }                                                                         \
  }
#define STEP_LAST(S, PS)                                                      \
  {                                                                           \
    const float4 d = PS;                                                      \
    const float* __restrict__ qc = qsh + (hcb + S) * (TQ * 4);                \
    _Pragma("unroll") for (int qi = 0; qi < TQ; ++qi) {                       \
      float4 qf = *(const float4*)(qc + qi * 4);                              \
      acc[qi] =                                                               \
          fmaf(qf.x, d.x, fmaf(qf.y, d.y, fmaf(qf.z, d.z, fmaf(qf.w, d.w, acc[qi])))); \
    }                                                                         \
  }
#pragma unroll 1
  for (int r = 0; r < 14; ++r) {
    const int hcb = r * 5;
    STEP(0, p0) STEP(1, p1) STEP(2, p2) STEP(3, p3) STEP(4, p4)
  }
  {
    const int hcb = 70;
    STEP_LAST(0, p0) STEP_LAST(1, p1) STEP_LAST(2, p2) STEP_LAST(3, p3) STEP_LAST(4, p4)
  }
#undef STEP
#undef STEP_LAST

  __syncthreads();
#pragma unroll
  for (int qi = 0; qi < TQ; ++qi) costmp[wave * 64 + lane][qi] = acc[qi] * invd;

  if (lane < TQ) {
    const int q = lane;
    float* tv = &topv[wave][q][0];
    float mn = tv[TOPK - 1];
    for (int tt = 0; tt < 64; ++tt) {
      float v = costmp[wave * 64 + tt][q];
      if (v > mn) {
        int p = TOPK - 1;
        while (p > 0 && tv[p - 1] < v) {
          tv[p] = tv[p - 1];
          --p;
        }
        tv[p] = v;
        mn = tv[TOPK - 1];
      }
    }
  }
  __syncthreads();

  if (tid < TQ) {
    const int q = tid;
    float* dst = &topv[0][q][0];
#pragma unroll
    for (int w = 1; w < 4; ++w) {
      for (int k = 0; k < TOPK; ++k) {
        float v = topv[w][q][k];
        if (v <= dst[TOPK - 1]) break;
        int p = TOPK - 1;
        while (p > 0 && dst[p - 1] < v) {
          dst[p] = dst[p - 1];
          --p;
        }
        dst[p] = v;
      }
    }
  }
  __syncthreads();

  for (int i = tid; i < TQ * TOPK; i += 256)
    partial[((size_t)(b * NCHUNK + chunk)) * (TQ * TOPK) + i] =
        topv[0][i / TOPK][i % TOPK];
}

// ---------------- Kernel 3: merge partials, FFW+tanh, gated softmax ----------------
__global__ __launch_bounds__(64) void finalize_kernel(
    const float* __restrict__ partial, const int* __restrict__ query,
    const float* __restrict__ qidf, const float* __restrict__ ffw_W,
    const float* __restrict__ ffw_b, const float* __restrict__ gates_W,
    const float* __restrict__ out_W, const float* __restrict__ out_b,
    float* __restrict__ out) {
  const int b = blockIdx.x;
  const int lane = (int)threadIdx.x;
  float ffw = 0.f;
  float logit = -3e38f;
  if (lane < TQ) {
    const int q = lane;
    int pos[NCHUNK];
#pragma unroll
    for (int c = 0; c < NCHUNK; ++c) pos[c] = 0;
    float s = 0.f;
    for (int k = 0; k < TOPK; ++k) {
      float best = -4.f;
      int bi = 0;
#pragma unroll
      for (int c = 0; c < NCHUNK; ++c) {
        float v = (pos[c] < TOPK)
                      ? partial[((size_t)(b * NCHUNK + c) * TQ + q) * TOPK + pos[c]]
                      : -4.f;
        if (v > best) {
          best = v;
          bi = c;
        }
      }
#pragma unroll
      for (int c = 0; c < NCHUNK; ++c)
        if (c == bi) pos[c]++;
      s += best * ffw_W[k];
    }
    ffw = tanhf(s + ffw_b[0]);
    int tok = query[b * TQ + q];
    logit = qidf[b * TQ + q] * gates_W[0] + (tok == 0 ? -1e7f : 0.f);
  }
  float m = logit;
#pragma unroll
  for (int off = 32; off; off >>= 1) m = fmaxf(m, __shfl_xor(m, off, 64));
  float e = expf(logit - m);
  float num = e * ffw;
  float den = e;
#pragma unroll
  for (int off = 32; off; off >>= 1) {
    num += __shfl_xor(num, off, 64);
    den += __shfl_xor(den, off, 64);
  }
  if (lane == 0) out[b] = (num / den) * out_W[0] + out_b[0];
}

extern "C" void kernel_launch(void* const* d_in, const int* in_sizes, int n_in,
                              void* d_out, int out_size, void* d_ws, size_t ws_size,
                              hipStream_t stream) {
  const int* doc = (const int*)d_in[0];
  const int* query = (const int*)d_in[1];
  const float* qidf = (const float*)d_in[2];
  const float* emb = (const float*)d_in[3];
  const float* ffw_W = (const float*)d_in[4];
  const float* ffw_b = (const float*)d_in[5];
  const float* gates_W = (const float*)d_in[6];
  const float* out_W = (const float*)d_in[7];
  const float* out_b = (const float*)d_in[8];
  float* out = (float*)d_out;

  char* ws = (char*)d_ws;
  float* invn = (float*)ws;  // fallback path only

  // MFMA-path layout (bytes): invn 200192 | qhi 2621440 | dhi 32000000 |
  // partial 5242880  => ~40MB total
  const size_t OFF_QHI = 200192;
  const size_t OFF_DHI = OFF_QHI + (size_t)NB * TQ * KP * 2;
  const size_t OFF_PAR = OFF_DHI + (size_t)VOCAB * KP * 2;
  const size_t NEED = OFF_PAR + (size_t)NB * NCHUNK * TQ * TOPK * 4;

  if (ws_size >= NEED) {
    ushort* qhi = (ushort*)(ws + OFF_QHI);
    ushort* dhi = (ushort*)(ws + OFF_DHI);
    float* partial = (float*)(ws + OFF_PAR);
    dprep_kernel<<<(VOCAB + 3) / 4, 256, 0, stream>>>(emb, dhi);
    qprep2_kernel<<<NB, 256, 0, stream>>>(query, emb, qhi);
    dim3 grid(NCHUNK, NB);
    mfma_topk_kernel<<<grid, 256, 0, stream>>>(doc, qhi, dhi, partial);
    finalize_kernel<<<NB, 64, 0, stream>>>(partial, query, qidf, ffw_W, ffw_b,
                                           gates_W, out_W, out_b, out);
  } else {
    // R5 fallback: invn | qn_t (1228800 f) | partial (1310720 f) ~ 10.4 MB
    float* qn_t = invn + 50048;
    float* partial = qn_t + (size_t)NB * NHC * TQ * 4;
    rownorm_kernel<<<(VOCAB + 3) / 4, 256, 0, stream>>>(emb, invn);
    qprep_kernel<<<NB, 256, 0, stream>>>(query, emb, invn, qn_t);
    dim3 grid(NCHUNK, NB);
    cos_topk_kernel<<<grid, 256, 0, stream>>>(doc, emb, invn, qn_t, partial);
    finalize_kernel<<<NB, 64, 0, stream>>>(partial, query, qidf, ffw_W, ffw_b,
                                           gates_W, out_W, out_b, out);
  }
}